// Round 5
// baseline (2196.406 us; speedup 1.0000x reference)
//
#include <hip/hip_runtime.h>
#include <math.h>

// ---------------------------------------------------------------------------
// 3-layer GCN, CSR-gather formulation.
// Round 5: register-tiled fp32 GEMM, straight-line (NO local arrays — the
// Round-4 version's xr[]/wr[] arrays were demoted to scratch: 1.7 GB FETCH +
// 1.3 GB WRITE of pure spill traffic).
// N=100000, E=1200000, F: 128 -> 64 -> 64 -> 40
// ---------------------------------------------------------------------------

static inline int cdiv(long a, int b) { return (int)((a + b - 1) / b); }

__global__ void k_zero_i32(int* __restrict__ p, int n) {
    int i = blockIdx.x * blockDim.x + threadIdx.x;
    if (i < n) p[i] = 0;
}

__global__ void k_hist(const int* __restrict__ dst, int* __restrict__ cnt, int E) {
    int i = blockIdx.x * blockDim.x + threadIdx.x;
    if (i < E) atomicAdd(&cnt[dst[i]], 1);
}

__global__ void k_dis(const int* __restrict__ cnt, float* __restrict__ dis, int n) {
    int i = blockIdx.x * blockDim.x + threadIdx.x;
    if (i < n) dis[i] = rsqrtf(1.0f + (float)cnt[i]);  // +1 self-loop
}

// ---- 3-step exclusive scan of cnt[0..n) into rp[0..n], rp[n]=E ----
#define SCAN_B 1024
__global__ void k_scan1(const int* __restrict__ cnt, int* __restrict__ rp,
                        int* __restrict__ bsum, int n) {
    __shared__ int sm[SCAN_B];
    const int tid = threadIdx.x;
    const int gid = blockIdx.x * SCAN_B + tid;
    int v = (gid < n) ? cnt[gid] : 0;
    sm[tid] = v;
    __syncthreads();
    for (int off = 1; off < SCAN_B; off <<= 1) {
        int t = (tid >= off) ? sm[tid - off] : 0;
        __syncthreads();
        sm[tid] += t;
        __syncthreads();
    }
    if (gid < n) rp[gid] = sm[tid] - v;           // exclusive
    if (tid == SCAN_B - 1) bsum[blockIdx.x] = sm[tid];
}

__global__ void k_scan2(int* __restrict__ bsum, int nb) {
    __shared__ int sm[SCAN_B];
    const int tid = threadIdx.x;
    int v = (tid < nb) ? bsum[tid] : 0;
    sm[tid] = v;
    __syncthreads();
    for (int off = 1; off < SCAN_B; off <<= 1) {
        int t = (tid >= off) ? sm[tid - off] : 0;
        __syncthreads();
        sm[tid] += t;
        __syncthreads();
    }
    if (tid < nb) bsum[tid] = sm[tid] - v;        // exclusive
}

__global__ void k_scan3(int* __restrict__ rp, const int* __restrict__ bsum, int n, int E) {
    const int gid = blockIdx.x * SCAN_B + threadIdx.x;
    if (gid < n) rp[gid] += bsum[gid / SCAN_B];
    if (gid == n) rp[n] = E;
}

// scatter (src, nrm) into CSR slots
__global__ void k_build(const int* __restrict__ src, const int* __restrict__ dst,
                        const float* __restrict__ dis, const int* __restrict__ rp,
                        int* __restrict__ fill, int2* __restrict__ edata, int E) {
    int e = blockIdx.x * blockDim.x + threadIdx.x;
    if (e >= E) return;
    int d = dst[e];
    int s = src[e];
    int pos = atomicAdd(&fill[d], 1);
    float nrm = dis[s] * dis[d];
    edata[rp[d] + pos] = make_int2(s, __float_as_int(nrm));
}

__device__ __forceinline__ void fma4(float a, const float4& w, float4& acc) {
    acc.x = fmaf(a, w.x, acc.x);
    acc.y = fmaf(a, w.y, acc.y);
    acc.z = fmaf(a, w.z, acc.z);
    acc.w = fmaf(a, w.w, acc.w);
}

// Register-tiled GEMM: H[N,64] = X[N,K] @ W[K,64].
// Block = 256 threads, 64 rows x 64 cols. Thread (tx,ty): cols tx*4..+3,
// rows ty*4..+3 -> 4 float4 accumulators. Straight-line, no local arrays.
template<int K>
__global__ void k_gemm_reg(const float* __restrict__ X, const float* __restrict__ W,
                           float* __restrict__ H, int N) {
    const int tx = threadIdx.x & 15;   // col group
    const int ty = threadIdx.x >> 4;   // row group (16 groups x 4 rows)
    const int row0 = blockIdx.x * 64 + ty * 4;
    const float4* W4 = (const float4*)W;       // W4[k*16 + tx] = W[k][4tx..4tx+3]

    // clamp rows for loads (duplicates harmless), guard stores below
    const float* x0 = X + (size_t)min(row0 + 0, N - 1) * K;
    const float* x1 = X + (size_t)min(row0 + 1, N - 1) * K;
    const float* x2 = X + (size_t)min(row0 + 2, N - 1) * K;
    const float* x3 = X + (size_t)min(row0 + 3, N - 1) * K;

    float4 acc0 = {0.f, 0.f, 0.f, 0.f};
    float4 acc1 = {0.f, 0.f, 0.f, 0.f};
    float4 acc2 = {0.f, 0.f, 0.f, 0.f};
    float4 acc3 = {0.f, 0.f, 0.f, 0.f};

#pragma unroll
    for (int k = 0; k < K; k += 4) {
        float4 w0 = W4[(k + 0) * 16 + tx];
        float4 w1 = W4[(k + 1) * 16 + tx];
        float4 w2 = W4[(k + 2) * 16 + tx];
        float4 w3 = W4[(k + 3) * 16 + tx];
        float4 xa = *(const float4*)(x0 + k);
        float4 xb = *(const float4*)(x1 + k);
        float4 xc = *(const float4*)(x2 + k);
        float4 xd = *(const float4*)(x3 + k);

        fma4(xa.x, w0, acc0); fma4(xa.y, w1, acc0); fma4(xa.z, w2, acc0); fma4(xa.w, w3, acc0);
        fma4(xb.x, w0, acc1); fma4(xb.y, w1, acc1); fma4(xb.z, w2, acc1); fma4(xb.w, w3, acc1);
        fma4(xc.x, w0, acc2); fma4(xc.y, w1, acc2); fma4(xc.z, w2, acc2); fma4(xc.w, w3, acc2);
        fma4(xd.x, w0, acc3); fma4(xd.y, w1, acc3); fma4(xd.z, w2, acc3); fma4(xd.w, w3, acc3);
    }

    float* hp = H + (size_t)row0 * 64 + tx * 4;
    if (row0 + 0 < N) *(float4*)(hp + 0 * 64) = acc0;
    if (row0 + 1 < N) *(float4*)(hp + 1 * 64) = acc1;
    if (row0 + 2 < N) *(float4*)(hp + 2 * 64) = acc2;
    if (row0 + 3 < N) *(float4*)(hp + 3 * 64) = acc3;
}

// Wave-per-node aggregation, F=64, unroll-4 for memory-level parallelism.
// A[node] = post( sum_in-edges H[src]*nrm + H[node]*dis^2 (+ bias) )
template<bool BIAS_RELU>
__global__ void k_agg64(const float* __restrict__ H, const float* __restrict__ dis,
                        const int* __restrict__ rp, const int2* __restrict__ edata,
                        const float* __restrict__ bias, float* __restrict__ A, int N) {
    const int wave = threadIdx.x >> 6;
    const int lane = threadIdx.x & 63;
    const int node = blockIdx.x * (blockDim.x >> 6) + wave;
    if (node >= N) return;
    const float dd = dis[node];
    float a0 = H[(size_t)node * 64 + lane] * dd * dd;  // self-loop
    float a1 = 0.f, a2 = 0.f, a3 = 0.f;
    int e = rp[node];
    const int e1 = rp[node + 1];
    for (; e + 4 <= e1; e += 4) {
        int2 p0 = edata[e + 0];
        int2 p1 = edata[e + 1];
        int2 p2 = edata[e + 2];
        int2 p3 = edata[e + 3];
        float h0 = H[(size_t)p0.x * 64 + lane];
        float h1 = H[(size_t)p1.x * 64 + lane];
        float h2 = H[(size_t)p2.x * 64 + lane];
        float h3 = H[(size_t)p3.x * 64 + lane];
        a0 = fmaf(h0, __int_as_float(p0.y), a0);
        a1 = fmaf(h1, __int_as_float(p1.y), a1);
        a2 = fmaf(h2, __int_as_float(p2.y), a2);
        a3 = fmaf(h3, __int_as_float(p3.y), a3);
    }
    for (; e < e1; ++e) {
        int2 p = edata[e];
        a0 = fmaf(H[(size_t)p.x * 64 + lane], __int_as_float(p.y), a0);
    }
    float acc = (a0 + a1) + (a2 + a3);
    if (BIAS_RELU) acc = fmaxf(acc + bias[lane], 0.0f);
    A[(size_t)node * 64 + lane] = acc;
}

// Final tiny GEMM: out[node,:40] = log_softmax( X[node,:64] @ W3[64,40] + b3 ).
// One wave per node; X-row held one value per lane, broadcast via shuffle.
__global__ void k_gemm40_lsm(const float* __restrict__ X, const float* __restrict__ W,
                             const float* __restrict__ bias, float* __restrict__ out, int N) {
    const int wave = threadIdx.x >> 6;
    const int lane = threadIdx.x & 63;
    const int node = blockIdx.x * (blockDim.x >> 6) + wave;
    if (node >= N) return;
    const float xv = X[(size_t)node * 64 + lane];
    const int cl = (lane < 40) ? lane : 0;   // clamp to keep W reads in-bounds
    float acc = 0.0f;
#pragma unroll
    for (int k = 0; k < 64; ++k) {
        float xk = __shfl(xv, k, 64);
        acc = fmaf(xk, W[k * 40 + cl], acc);
    }
    float v = (lane < 40) ? acc + bias[cl] : -INFINITY;
    float m = v;
#pragma unroll
    for (int o = 32; o > 0; o >>= 1) m = fmaxf(m, __shfl_xor(m, o, 64));
    float ex = (lane < 40) ? expf(v - m) : 0.0f;
    float ssum = ex;
#pragma unroll
    for (int o = 32; o > 0; o >>= 1) ssum += __shfl_xor(ssum, o, 64);
    if (lane < 40) out[(size_t)node * 40 + lane] = v - m - logf(ssum);
}

extern "C" void kernel_launch(void* const* d_in, const int* in_sizes, int n_in,
                              void* d_out, int out_size, void* d_ws, size_t ws_size,
                              hipStream_t stream) {
    const float* x  = (const float*)d_in[0];
    const int*   ei = (const int*)d_in[1];
    const float* W1 = (const float*)d_in[2];
    const float* b1 = (const float*)d_in[3];
    const float* W2 = (const float*)d_in[4];
    const float* b2 = (const float*)d_in[5];
    const float* W3 = (const float*)d_in[6];
    const float* b3 = (const float*)d_in[7];
    float* out = (float*)d_out;

    const int N = in_sizes[0] / 128;
    const int E = in_sizes[1] / 2;
    const int* src = ei;
    const int* dst = ei + E;

    // ---- workspace layout (8B-aligned first) ----
    char* ws = (char*)d_ws;
    int2*  edata = (int2*)ws;                 ws += (size_t)E * sizeof(int2);       // 9.6 MB
    float* hbuf  = (float*)ws;                ws += (size_t)N * 64 * sizeof(float); // 25.6 MB
    float* abuf  = (float*)ws;                ws += (size_t)N * 64 * sizeof(float); // 25.6 MB
    int*   cnt   = (int*)ws;                  ws += (size_t)N * sizeof(int);
    int*   fill  = (int*)ws;                  ws += (size_t)N * sizeof(int);
    int*   rp    = (int*)ws;                  ws += (size_t)(N + 1) * sizeof(int);
    int*   bsum  = (int*)ws;                  ws += (size_t)SCAN_B * sizeof(int);
    float* dis   = (float*)ws;                ws += (size_t)N * sizeof(float);

    const int B = 256;
    const int nb = cdiv(N, SCAN_B);

    // ---- CSR build ----
    k_zero_i32<<<cdiv(2 * N, B), B, 0, stream>>>(cnt, 2 * N);  // cnt + fill adjacent
    k_hist<<<cdiv(E, B), B, 0, stream>>>(dst, cnt, E);
    k_dis<<<cdiv(N, B), B, 0, stream>>>(cnt, dis, N);
    k_scan1<<<nb, SCAN_B, 0, stream>>>(cnt, rp, bsum, N);
    k_scan2<<<1, SCAN_B, 0, stream>>>(bsum, nb);
    k_scan3<<<cdiv(N + 1, SCAN_B), SCAN_B, 0, stream>>>(rp, bsum, N, E);
    k_build<<<cdiv(E, B), B, 0, stream>>>(src, dst, dis, rp, fill, edata, E);

    // ---- layer 1: x[N,128] @ W1 -> hbuf; aggregate+bias+relu -> abuf ----
    k_gemm_reg<128><<<cdiv(N, 64), B, 0, stream>>>(x, W1, hbuf, N);
    k_agg64<true><<<cdiv(N, 4), B, 0, stream>>>(hbuf, dis, rp, edata, b1, abuf, N);

    // ---- layer 2 ----
    k_gemm_reg<64><<<cdiv(N, 64), B, 0, stream>>>(abuf, W2, hbuf, N);
    k_agg64<true><<<cdiv(N, 4), B, 0, stream>>>(hbuf, dis, rp, edata, b2, abuf, N);

    // ---- layer 3 reordered: (A h2) W3 + b3 -> log_softmax ----
    k_agg64<false><<<cdiv(N, 4), B, 0, stream>>>(abuf, dis, rp, edata, nullptr, hbuf, N);
    k_gemm40_lsm<<<cdiv(N, 4), B, 0, stream>>>(hbuf, W3, b3, out, N);
}

// Round 6
// 561.643 us; speedup vs baseline: 3.9107x; 3.9107x over previous
//
#include <hip/hip_runtime.h>
#include <math.h>

// ---------------------------------------------------------------------------
// 3-layer GCN, CSR-gather formulation.
// Round 6: register-tiled fp32 GEMM with __launch_bounds__(256,2).
// Rounds 4/5 spilled: compiler capped VGPRs at 64 (occupancy heuristic) and
// spilled the ~90-reg working set to scratch -> 1.8 GB FETCH + 1.3 GB WRITE.
// launch_bounds raises the cap to 256 VGPRs (2 waves/SIMD), eliminating spill.
// N=100000, E=1200000, F: 128 -> 64 -> 64 -> 40
// ---------------------------------------------------------------------------

static inline int cdiv(long a, int b) { return (int)((a + b - 1) / b); }

__global__ void k_zero_i32(int* __restrict__ p, int n) {
    int i = blockIdx.x * blockDim.x + threadIdx.x;
    if (i < n) p[i] = 0;
}

__global__ void k_hist(const int* __restrict__ dst, int* __restrict__ cnt, int E) {
    int i = blockIdx.x * blockDim.x + threadIdx.x;
    if (i < E) atomicAdd(&cnt[dst[i]], 1);
}

__global__ void k_dis(const int* __restrict__ cnt, float* __restrict__ dis, int n) {
    int i = blockIdx.x * blockDim.x + threadIdx.x;
    if (i < n) dis[i] = rsqrtf(1.0f + (float)cnt[i]);  // +1 self-loop
}

// ---- 3-step exclusive scan of cnt[0..n) into rp[0..n], rp[n]=E ----
#define SCAN_B 1024
__global__ void k_scan1(const int* __restrict__ cnt, int* __restrict__ rp,
                        int* __restrict__ bsum, int n) {
    __shared__ int sm[SCAN_B];
    const int tid = threadIdx.x;
    const int gid = blockIdx.x * SCAN_B + tid;
    int v = (gid < n) ? cnt[gid] : 0;
    sm[tid] = v;
    __syncthreads();
    for (int off = 1; off < SCAN_B; off <<= 1) {
        int t = (tid >= off) ? sm[tid - off] : 0;
        __syncthreads();
        sm[tid] += t;
        __syncthreads();
    }
    if (gid < n) rp[gid] = sm[tid] - v;           // exclusive
    if (tid == SCAN_B - 1) bsum[blockIdx.x] = sm[tid];
}

__global__ void k_scan2(int* __restrict__ bsum, int nb) {
    __shared__ int sm[SCAN_B];
    const int tid = threadIdx.x;
    int v = (tid < nb) ? bsum[tid] : 0;
    sm[tid] = v;
    __syncthreads();
    for (int off = 1; off < SCAN_B; off <<= 1) {
        int t = (tid >= off) ? sm[tid - off] : 0;
        __syncthreads();
        sm[tid] += t;
        __syncthreads();
    }
    if (tid < nb) bsum[tid] = sm[tid] - v;        // exclusive
}

__global__ void k_scan3(int* __restrict__ rp, const int* __restrict__ bsum, int n, int E) {
    const int gid = blockIdx.x * SCAN_B + threadIdx.x;
    if (gid < n) rp[gid] += bsum[gid / SCAN_B];
    if (gid == n) rp[n] = E;
}

// scatter (src, nrm) into CSR slots
__global__ void k_build(const int* __restrict__ src, const int* __restrict__ dst,
                        const float* __restrict__ dis, const int* __restrict__ rp,
                        int* __restrict__ fill, int2* __restrict__ edata, int E) {
    int e = blockIdx.x * blockDim.x + threadIdx.x;
    if (e >= E) return;
    int d = dst[e];
    int s = src[e];
    int pos = atomicAdd(&fill[d], 1);
    float nrm = dis[s] * dis[d];
    edata[rp[d] + pos] = make_int2(s, __float_as_int(nrm));
}

__device__ __forceinline__ void fma4(float a, const float4& w, float4& acc) {
    acc.x = fmaf(a, w.x, acc.x);
    acc.y = fmaf(a, w.y, acc.y);
    acc.z = fmaf(a, w.z, acc.z);
    acc.w = fmaf(a, w.w, acc.w);
}

// Register-tiled GEMM: H[N,64] = X[N,K] @ W[K,64].
// Block = 256 threads, 64 rows x 64 cols. Thread (tx,ty): cols tx*4..+3,
// rows ty*4..+3 -> 4 float4 accumulators. launch_bounds(256,2): VGPR cap 256.
template<int K>
__global__ __launch_bounds__(256, 2)
void k_gemm_reg(const float* __restrict__ X, const float* __restrict__ W,
                float* __restrict__ H, int N) {
    const int tx = threadIdx.x & 15;   // col group
    const int ty = threadIdx.x >> 4;   // row group (16 groups x 4 rows)
    const int row0 = blockIdx.x * 64 + ty * 4;
    const float4* W4 = (const float4*)W;       // W4[k*16 + tx] = W[k][4tx..4tx+3]

    // clamp rows for loads (duplicates harmless), guard stores below
    const float* x0 = X + (size_t)min(row0 + 0, N - 1) * K;
    const float* x1 = X + (size_t)min(row0 + 1, N - 1) * K;
    const float* x2 = X + (size_t)min(row0 + 2, N - 1) * K;
    const float* x3 = X + (size_t)min(row0 + 3, N - 1) * K;

    float4 acc0 = {0.f, 0.f, 0.f, 0.f};
    float4 acc1 = {0.f, 0.f, 0.f, 0.f};
    float4 acc2 = {0.f, 0.f, 0.f, 0.f};
    float4 acc3 = {0.f, 0.f, 0.f, 0.f};

#pragma unroll 2
    for (int k = 0; k < K; k += 4) {
        float4 w0 = W4[(k + 0) * 16 + tx];
        float4 w1 = W4[(k + 1) * 16 + tx];
        float4 w2 = W4[(k + 2) * 16 + tx];
        float4 w3 = W4[(k + 3) * 16 + tx];
        float4 xa = *(const float4*)(x0 + k);
        float4 xb = *(const float4*)(x1 + k);
        float4 xc = *(const float4*)(x2 + k);
        float4 xd = *(const float4*)(x3 + k);

        fma4(xa.x, w0, acc0); fma4(xa.y, w1, acc0); fma4(xa.z, w2, acc0); fma4(xa.w, w3, acc0);
        fma4(xb.x, w0, acc1); fma4(xb.y, w1, acc1); fma4(xb.z, w2, acc1); fma4(xb.w, w3, acc1);
        fma4(xc.x, w0, acc2); fma4(xc.y, w1, acc2); fma4(xc.z, w2, acc2); fma4(xc.w, w3, acc2);
        fma4(xd.x, w0, acc3); fma4(xd.y, w1, acc3); fma4(xd.z, w2, acc3); fma4(xd.w, w3, acc3);
    }

    float* hp = H + (size_t)row0 * 64 + tx * 4;
    if (row0 + 0 < N) *(float4*)(hp + 0 * 64) = acc0;
    if (row0 + 1 < N) *(float4*)(hp + 1 * 64) = acc1;
    if (row0 + 2 < N) *(float4*)(hp + 2 * 64) = acc2;
    if (row0 + 3 < N) *(float4*)(hp + 3 * 64) = acc3;
}

// Wave-per-node aggregation, F=64, unroll-4 for memory-level parallelism.
// A[node] = post( sum_in-edges H[src]*nrm + H[node]*dis^2 (+ bias) )
template<bool BIAS_RELU>
__global__ void k_agg64(const float* __restrict__ H, const float* __restrict__ dis,
                        const int* __restrict__ rp, const int2* __restrict__ edata,
                        const float* __restrict__ bias, float* __restrict__ A, int N) {
    const int wave = threadIdx.x >> 6;
    const int lane = threadIdx.x & 63;
    const int node = blockIdx.x * (blockDim.x >> 6) + wave;
    if (node >= N) return;
    const float dd = dis[node];
    float a0 = H[(size_t)node * 64 + lane] * dd * dd;  // self-loop
    float a1 = 0.f, a2 = 0.f, a3 = 0.f;
    int e = rp[node];
    const int e1 = rp[node + 1];
    for (; e + 4 <= e1; e += 4) {
        int2 p0 = edata[e + 0];
        int2 p1 = edata[e + 1];
        int2 p2 = edata[e + 2];
        int2 p3 = edata[e + 3];
        float h0 = H[(size_t)p0.x * 64 + lane];
        float h1 = H[(size_t)p1.x * 64 + lane];
        float h2 = H[(size_t)p2.x * 64 + lane];
        float h3 = H[(size_t)p3.x * 64 + lane];
        a0 = fmaf(h0, __int_as_float(p0.y), a0);
        a1 = fmaf(h1, __int_as_float(p1.y), a1);
        a2 = fmaf(h2, __int_as_float(p2.y), a2);
        a3 = fmaf(h3, __int_as_float(p3.y), a3);
    }
    for (; e < e1; ++e) {
        int2 p = edata[e];
        a0 = fmaf(H[(size_t)p.x * 64 + lane], __int_as_float(p.y), a0);
    }
    float acc = (a0 + a1) + (a2 + a3);
    if (BIAS_RELU) acc = fmaxf(acc + bias[lane], 0.0f);
    A[(size_t)node * 64 + lane] = acc;
}

// Final tiny GEMM: out[node,:40] = log_softmax( X[node,:64] @ W3[64,40] + b3 ).
// One wave per node; X-row held one value per lane, broadcast via shuffle.
__global__ void k_gemm40_lsm(const float* __restrict__ X, const float* __restrict__ W,
                             const float* __restrict__ bias, float* __restrict__ out, int N) {
    const int wave = threadIdx.x >> 6;
    const int lane = threadIdx.x & 63;
    const int node = blockIdx.x * (blockDim.x >> 6) + wave;
    if (node >= N) return;
    const float xv = X[(size_t)node * 64 + lane];
    const int cl = (lane < 40) ? lane : 0;   // clamp to keep W reads in-bounds
    float acc = 0.0f;
#pragma unroll
    for (int k = 0; k < 64; ++k) {
        float xk = __shfl(xv, k, 64);
        acc = fmaf(xk, W[k * 40 + cl], acc);
    }
    float v = (lane < 40) ? acc + bias[cl] : -INFINITY;
    float m = v;
#pragma unroll
    for (int o = 32; o > 0; o >>= 1) m = fmaxf(m, __shfl_xor(m, o, 64));
    float ex = (lane < 40) ? expf(v - m) : 0.0f;
    float ssum = ex;
#pragma unroll
    for (int o = 32; o > 0; o >>= 1) ssum += __shfl_xor(ssum, o, 64);
    if (lane < 40) out[(size_t)node * 40 + lane] = v - m - logf(ssum);
}

extern "C" void kernel_launch(void* const* d_in, const int* in_sizes, int n_in,
                              void* d_out, int out_size, void* d_ws, size_t ws_size,
                              hipStream_t stream) {
    const float* x  = (const float*)d_in[0];
    const int*   ei = (const int*)d_in[1];
    const float* W1 = (const float*)d_in[2];
    const float* b1 = (const float*)d_in[3];
    const float* W2 = (const float*)d_in[4];
    const float* b2 = (const float*)d_in[5];
    const float* W3 = (const float*)d_in[6];
    const float* b3 = (const float*)d_in[7];
    float* out = (float*)d_out;

    const int N = in_sizes[0] / 128;
    const int E = in_sizes[1] / 2;
    const int* src = ei;
    const int* dst = ei + E;

    // ---- workspace layout (8B-aligned first) ----
    char* ws = (char*)d_ws;
    int2*  edata = (int2*)ws;                 ws += (size_t)E * sizeof(int2);       // 9.6 MB
    float* hbuf  = (float*)ws;                ws += (size_t)N * 64 * sizeof(float); // 25.6 MB
    float* abuf  = (float*)ws;                ws += (size_t)N * 64 * sizeof(float); // 25.6 MB
    int*   cnt   = (int*)ws;                  ws += (size_t)N * sizeof(int);
    int*   fill  = (int*)ws;                  ws += (size_t)N * sizeof(int);
    int*   rp    = (int*)ws;                  ws += (size_t)(N + 1) * sizeof(int);
    int*   bsum  = (int*)ws;                  ws += (size_t)SCAN_B * sizeof(int);
    float* dis   = (float*)ws;                ws += (size_t)N * sizeof(float);

    const int B = 256;
    const int nb = cdiv(N, SCAN_B);

    // ---- CSR build ----
    k_zero_i32<<<cdiv(2 * N, B), B, 0, stream>>>(cnt, 2 * N);  // cnt + fill adjacent
    k_hist<<<cdiv(E, B), B, 0, stream>>>(dst, cnt, E);
    k_dis<<<cdiv(N, B), B, 0, stream>>>(cnt, dis, N);
    k_scan1<<<nb, SCAN_B, 0, stream>>>(cnt, rp, bsum, N);
    k_scan2<<<1, SCAN_B, 0, stream>>>(bsum, nb);
    k_scan3<<<cdiv(N + 1, SCAN_B), SCAN_B, 0, stream>>>(rp, bsum, N, E);
    k_build<<<cdiv(E, B), B, 0, stream>>>(src, dst, dis, rp, fill, edata, E);

    // ---- layer 1: x[N,128] @ W1 -> hbuf; aggregate+bias+relu -> abuf ----
    k_gemm_reg<128><<<cdiv(N, 64), B, 0, stream>>>(x, W1, hbuf, N);
    k_agg64<true><<<cdiv(N, 4), B, 0, stream>>>(hbuf, dis, rp, edata, b1, abuf, N);

    // ---- layer 2 ----
    k_gemm_reg<64><<<cdiv(N, 64), B, 0, stream>>>(abuf, W2, hbuf, N);
    k_agg64<true><<<cdiv(N, 4), B, 0, stream>>>(hbuf, dis, rp, edata, b2, abuf, N);

    // ---- layer 3 reordered: (A h2) W3 + b3 -> log_softmax ----
    k_agg64<false><<<cdiv(N, 4), B, 0, stream>>>(abuf, dis, rp, edata, nullptr, hbuf, N);
    k_gemm40_lsm<<<cdiv(N, 4), B, 0, stream>>>(hbuf, W3, b3, out, N);
}

// Round 7
// 515.695 us; speedup vs baseline: 4.2591x; 1.0891x over previous
//
#include <hip/hip_runtime.h>
#include <math.h>

// ---------------------------------------------------------------------------
// 3-layer GCN, CSR-gather formulation.
// Round 7: final layer's 64->40 GEMM+log_softmax rebuilt: the shuffle-
// broadcast version did 64 ds_bpermute per node (LDS-pipe bound, 90us).
// New k_w3lsm: W3 column pinned in 64 VGPRs per lane, X row read via
// wave-uniform loads, zero per-k cross-lane ops. ~7us memory floor.
// N=100000, E=1200000, F: 128 -> 64 -> 64 -> 40
// ---------------------------------------------------------------------------

static inline int cdiv(long a, int b) { return (int)((a + b - 1) / b); }

__global__ void k_zero_i32(int* __restrict__ p, int n) {
    int i = blockIdx.x * blockDim.x + threadIdx.x;
    if (i < n) p[i] = 0;
}

__global__ void k_hist(const int* __restrict__ dst, int* __restrict__ cnt, int E) {
    int i = blockIdx.x * blockDim.x + threadIdx.x;
    if (i < E) atomicAdd(&cnt[dst[i]], 1);
}

__global__ void k_dis(const int* __restrict__ cnt, float* __restrict__ dis, int n) {
    int i = blockIdx.x * blockDim.x + threadIdx.x;
    if (i < n) dis[i] = rsqrtf(1.0f + (float)cnt[i]);  // +1 self-loop
}

// ---- 3-step exclusive scan of cnt[0..n) into rp[0..n], rp[n]=E ----
#define SCAN_B 1024
__global__ void k_scan1(const int* __restrict__ cnt, int* __restrict__ rp,
                        int* __restrict__ bsum, int n) {
    __shared__ int sm[SCAN_B];
    const int tid = threadIdx.x;
    const int gid = blockIdx.x * SCAN_B + tid;
    int v = (gid < n) ? cnt[gid] : 0;
    sm[tid] = v;
    __syncthreads();
    for (int off = 1; off < SCAN_B; off <<= 1) {
        int t = (tid >= off) ? sm[tid - off] : 0;
        __syncthreads();
        sm[tid] += t;
        __syncthreads();
    }
    if (gid < n) rp[gid] = sm[tid] - v;           // exclusive
    if (tid == SCAN_B - 1) bsum[blockIdx.x] = sm[tid];
}

__global__ void k_scan2(int* __restrict__ bsum, int nb) {
    __shared__ int sm[SCAN_B];
    const int tid = threadIdx.x;
    int v = (tid < nb) ? bsum[tid] : 0;
    sm[tid] = v;
    __syncthreads();
    for (int off = 1; off < SCAN_B; off <<= 1) {
        int t = (tid >= off) ? sm[tid - off] : 0;
        __syncthreads();
        sm[tid] += t;
        __syncthreads();
    }
    if (tid < nb) bsum[tid] = sm[tid] - v;        // exclusive
}

__global__ void k_scan3(int* __restrict__ rp, const int* __restrict__ bsum, int n, int E) {
    const int gid = blockIdx.x * SCAN_B + threadIdx.x;
    if (gid < n) rp[gid] += bsum[gid / SCAN_B];
    if (gid == n) rp[n] = E;
}

// scatter (src, nrm) into CSR slots
__global__ void k_build(const int* __restrict__ src, const int* __restrict__ dst,
                        const float* __restrict__ dis, const int* __restrict__ rp,
                        int* __restrict__ fill, int2* __restrict__ edata, int E) {
    int e = blockIdx.x * blockDim.x + threadIdx.x;
    if (e >= E) return;
    int d = dst[e];
    int s = src[e];
    int pos = atomicAdd(&fill[d], 1);
    float nrm = dis[s] * dis[d];
    edata[rp[d] + pos] = make_int2(s, __float_as_int(nrm));
}

__device__ __forceinline__ void fma4(float a, const float4& w, float4& acc) {
    acc.x = fmaf(a, w.x, acc.x);
    acc.y = fmaf(a, w.y, acc.y);
    acc.z = fmaf(a, w.z, acc.z);
    acc.w = fmaf(a, w.w, acc.w);
}

// Register-tiled GEMM: H[N,64] = X[N,K] @ W[K,64].
// Block = 256 threads, 64 rows x 64 cols. launch_bounds(256,2): VGPR cap 256.
template<int K>
__global__ __launch_bounds__(256, 2)
void k_gemm_reg(const float* __restrict__ X, const float* __restrict__ W,
                float* __restrict__ H, int N) {
    const int tx = threadIdx.x & 15;   // col group
    const int ty = threadIdx.x >> 4;   // row group (16 groups x 4 rows)
    const int row0 = blockIdx.x * 64 + ty * 4;
    const float4* W4 = (const float4*)W;       // W4[k*16 + tx] = W[k][4tx..4tx+3]

    const float* x0 = X + (size_t)min(row0 + 0, N - 1) * K;
    const float* x1 = X + (size_t)min(row0 + 1, N - 1) * K;
    const float* x2 = X + (size_t)min(row0 + 2, N - 1) * K;
    const float* x3 = X + (size_t)min(row0 + 3, N - 1) * K;

    float4 acc0 = {0.f, 0.f, 0.f, 0.f};
    float4 acc1 = {0.f, 0.f, 0.f, 0.f};
    float4 acc2 = {0.f, 0.f, 0.f, 0.f};
    float4 acc3 = {0.f, 0.f, 0.f, 0.f};

#pragma unroll 2
    for (int k = 0; k < K; k += 4) {
        float4 w0 = W4[(k + 0) * 16 + tx];
        float4 w1 = W4[(k + 1) * 16 + tx];
        float4 w2 = W4[(k + 2) * 16 + tx];
        float4 w3 = W4[(k + 3) * 16 + tx];
        float4 xa = *(const float4*)(x0 + k);
        float4 xb = *(const float4*)(x1 + k);
        float4 xc = *(const float4*)(x2 + k);
        float4 xd = *(const float4*)(x3 + k);

        fma4(xa.x, w0, acc0); fma4(xa.y, w1, acc0); fma4(xa.z, w2, acc0); fma4(xa.w, w3, acc0);
        fma4(xb.x, w0, acc1); fma4(xb.y, w1, acc1); fma4(xb.z, w2, acc1); fma4(xb.w, w3, acc1);
        fma4(xc.x, w0, acc2); fma4(xc.y, w1, acc2); fma4(xc.z, w2, acc2); fma4(xc.w, w3, acc2);
        fma4(xd.x, w0, acc3); fma4(xd.y, w1, acc3); fma4(xd.z, w2, acc3); fma4(xd.w, w3, acc3);
    }

    float* hp = H + (size_t)row0 * 64 + tx * 4;
    if (row0 + 0 < N) *(float4*)(hp + 0 * 64) = acc0;
    if (row0 + 1 < N) *(float4*)(hp + 1 * 64) = acc1;
    if (row0 + 2 < N) *(float4*)(hp + 2 * 64) = acc2;
    if (row0 + 3 < N) *(float4*)(hp + 3 * 64) = acc3;
}

// Wave-per-node aggregation, F=64, unroll-4 for memory-level parallelism.
template<bool BIAS_RELU>
__global__ void k_agg64(const float* __restrict__ H, const float* __restrict__ dis,
                        const int* __restrict__ rp, const int2* __restrict__ edata,
                        const float* __restrict__ bias, float* __restrict__ A, int N) {
    const int wave = threadIdx.x >> 6;
    const int lane = threadIdx.x & 63;
    const int node = blockIdx.x * (blockDim.x >> 6) + wave;
    if (node >= N) return;
    const float dd = dis[node];
    float a0 = H[(size_t)node * 64 + lane] * dd * dd;  // self-loop
    float a1 = 0.f, a2 = 0.f, a3 = 0.f;
    int e = rp[node];
    const int e1 = rp[node + 1];
    for (; e + 4 <= e1; e += 4) {
        int2 p0 = edata[e + 0];
        int2 p1 = edata[e + 1];
        int2 p2 = edata[e + 2];
        int2 p3 = edata[e + 3];
        float h0 = H[(size_t)p0.x * 64 + lane];
        float h1 = H[(size_t)p1.x * 64 + lane];
        float h2 = H[(size_t)p2.x * 64 + lane];
        float h3 = H[(size_t)p3.x * 64 + lane];
        a0 = fmaf(h0, __int_as_float(p0.y), a0);
        a1 = fmaf(h1, __int_as_float(p1.y), a1);
        a2 = fmaf(h2, __int_as_float(p2.y), a2);
        a3 = fmaf(h3, __int_as_float(p3.y), a3);
    }
    for (; e < e1; ++e) {
        int2 p = edata[e];
        a0 = fmaf(H[(size_t)p.x * 64 + lane], __int_as_float(p.y), a0);
    }
    float acc = (a0 + a1) + (a2 + a3);
    if (BIAS_RELU) acc = fmaxf(acc + bias[lane], 0.0f);
    A[(size_t)node * 64 + lane] = acc;
}

// Final layer: out[n,:40] = log_softmax(X[n,:64] @ W3 + b3).
// Lane c holds W3[:,c] in 64 VGPRs (loaded once per wave); per node the
// X row is read via wave-uniform address (broadcast / scalar loads) — zero
// per-k cross-lane ops. launch_bounds(256,4): 128-VGPR cap, no spill.
__global__ __launch_bounds__(256, 4)
void k_w3lsm(const float* __restrict__ X, const float* __restrict__ W,
             const float* __restrict__ bias, float* __restrict__ out,
             int N, int npw) {
    const int wid  = blockIdx.x * (blockDim.x >> 6) + (threadIdx.x >> 6);
    const int lane = threadIdx.x & 63;
    const int cl   = (lane < 40) ? lane : 0;

    float w[64];
#pragma unroll
    for (int k = 0; k < 64; ++k) w[k] = W[k * 40 + cl];
    const float bv = bias[cl];

    const int n0 = wid * npw;
    const int n1 = min(n0 + npw, N);
    for (int node = n0; node < n1; ++node) {
        const int un = __builtin_amdgcn_readfirstlane(node);
        const float4* xr = (const float4*)(X + (size_t)un * 64);
        float acc = 0.0f;
#pragma unroll
        for (int j = 0; j < 16; ++j) {
            float4 xv = xr[j];
            acc = fmaf(xv.x, w[4 * j + 0], acc);
            acc = fmaf(xv.y, w[4 * j + 1], acc);
            acc = fmaf(xv.z, w[4 * j + 2], acc);
            acc = fmaf(xv.w, w[4 * j + 3], acc);
        }
        float v = (lane < 40) ? acc + bv : -INFINITY;
        float m = v;
#pragma unroll
        for (int o = 32; o > 0; o >>= 1) m = fmaxf(m, __shfl_xor(m, o, 64));
        float ex = (lane < 40) ? expf(v - m) : 0.0f;
        float s = ex;
#pragma unroll
        for (int o = 32; o > 0; o >>= 1) s += __shfl_xor(s, o, 64);
        if (lane < 40) out[(size_t)node * 40 + lane] = v - m - logf(s);
    }
}

extern "C" void kernel_launch(void* const* d_in, const int* in_sizes, int n_in,
                              void* d_out, int out_size, void* d_ws, size_t ws_size,
                              hipStream_t stream) {
    const float* x  = (const float*)d_in[0];
    const int*   ei = (const int*)d_in[1];
    const float* W1 = (const float*)d_in[2];
    const float* b1 = (const float*)d_in[3];
    const float* W2 = (const float*)d_in[4];
    const float* b2 = (const float*)d_in[5];
    const float* W3 = (const float*)d_in[6];
    const float* b3 = (const float*)d_in[7];
    float* out = (float*)d_out;

    const int N = in_sizes[0] / 128;
    const int E = in_sizes[1] / 2;
    const int* src = ei;
    const int* dst = ei + E;

    // ---- workspace layout (8B-aligned first) ----
    char* ws = (char*)d_ws;
    int2*  edata = (int2*)ws;                 ws += (size_t)E * sizeof(int2);       // 9.6 MB
    float* hbuf  = (float*)ws;                ws += (size_t)N * 64 * sizeof(float); // 25.6 MB
    float* abuf  = (float*)ws;                ws += (size_t)N * 64 * sizeof(float); // 25.6 MB
    int*   cnt   = (int*)ws;                  ws += (size_t)N * sizeof(int);
    int*   fill  = (int*)ws;                  ws += (size_t)N * sizeof(int);
    int*   rp    = (int*)ws;                  ws += (size_t)(N + 1) * sizeof(int);
    int*   bsum  = (int*)ws;                  ws += (size_t)SCAN_B * sizeof(int);
    float* dis   = (float*)ws;                ws += (size_t)N * sizeof(float);

    const int B = 256;
    const int nb = cdiv(N, SCAN_B);

    // ---- CSR build ----
    k_zero_i32<<<cdiv(2 * N, B), B, 0, stream>>>(cnt, 2 * N);  // cnt + fill adjacent
    k_hist<<<cdiv(E, B), B, 0, stream>>>(dst, cnt, E);
    k_dis<<<cdiv(N, B), B, 0, stream>>>(cnt, dis, N);
    k_scan1<<<nb, SCAN_B, 0, stream>>>(cnt, rp, bsum, N);
    k_scan2<<<1, SCAN_B, 0, stream>>>(bsum, nb);
    k_scan3<<<cdiv(N + 1, SCAN_B), SCAN_B, 0, stream>>>(rp, bsum, N, E);
    k_build<<<cdiv(E, B), B, 0, stream>>>(src, dst, dis, rp, fill, edata, E);

    // ---- layer 1: x[N,128] @ W1 -> hbuf; aggregate+bias+relu -> abuf ----
    k_gemm_reg<128><<<cdiv(N, 64), B, 0, stream>>>(x, W1, hbuf, N);
    k_agg64<true><<<cdiv(N, 4), B, 0, stream>>>(hbuf, dis, rp, edata, b1, abuf, N);

    // ---- layer 2 ----
    k_gemm_reg<64><<<cdiv(N, 64), B, 0, stream>>>(abuf, W2, hbuf, N);
    k_agg64<true><<<cdiv(N, 4), B, 0, stream>>>(hbuf, dis, rp, edata, b2, abuf, N);

    // ---- layer 3 reordered: (A h2) W3 + b3 -> log_softmax ----
    k_agg64<false><<<cdiv(N, 4), B, 0, stream>>>(abuf, dis, rp, edata, nullptr, hbuf, N);
    const int nwaves = 4096;                       // 1024 blocks x 4 waves
    const int npw = cdiv(N, nwaves);
    k_w3lsm<<<nwaves / 4, B, 0, stream>>>(hbuf, W3, b3, out, N, npw);
}